// Round 13
// baseline (204.647 us; speedup 1.0000x reference)
//
#include <hip/hip_runtime.h>
#include <hip/hip_bf16.h>

#define DEVINL __device__ __forceinline__

typedef short bf16x8 __attribute__((ext_vector_type(8)));
typedef float f32x4  __attribute__((ext_vector_type(4)));
typedef float f32x16 __attribute__((ext_vector_type(16)));
typedef unsigned int uint2v __attribute__((ext_vector_type(2)));

struct alignas(8) S4 { short x, y, z, w; };

DEVINL short f2bf(float f) {
  __hip_bfloat16 h = __float2bfloat16(f);
  short s; __builtin_memcpy(&s, &h, 2); return s;
}
DEVINL float bf2f(short s) {
  unsigned u = ((unsigned)(unsigned short)s) << 16;
  float f; __builtin_memcpy(&f, &u, 4); return f;
}

DEVINL f32x4 mfma16(bf16x8 a, bf16x8 b, f32x4 c) {
  return __builtin_amdgcn_mfma_f32_16x16x32_bf16(a, b, c, 0, 0, 0);
}
DEVINL f32x16 mfma32(bf16x8 a, bf16x8 b, f32x16 c) {
  return __builtin_amdgcn_mfma_f32_32x32x16_bf16(a, b, c, 0, 0, 0);
}

// async global->LDS, 16B per lane; LDS dest is wave-uniform base (+lane*16 by HW)
DEVINL void gld_lds16(const void* gptr, void* lptr) {
  __builtin_amdgcn_global_load_lds(
      (const __attribute__((address_space(1))) unsigned int*)gptr,
      (__attribute__((address_space(3))) unsigned int*)lptr, 16, 0, 0);
}

#define CC 256
#define C4 64
#define BB 2
#define NQ 8192
#define NK 8192
#define NROWS (BB * NQ)
#define LOG2E 1.44269504f

// ---------------- setup: weights -> bf16 (wq pre-scaled by log2e), BN fold ---
__global__ void k_setup(const float* __restrict__ wq, const float* __restrict__ wk,
                        const float* __restrict__ wv, const float* __restrict__ wt,
                        const float* __restrict__ bt, const float* __restrict__ gmm,
                        const float* __restrict__ bet, const float* __restrict__ rmean,
                        const float* __restrict__ rvar,
                        short* __restrict__ wqb, short* __restrict__ wkb,
                        short* __restrict__ wvb, short* __restrict__ wtb,
                        float* __restrict__ scale, float* __restrict__ bias) {
  int i = blockIdx.x * 256 + threadIdx.x;
  if (i < C4 * CC) { wqb[i] = f2bf(wq[i] * LOG2E); wkb[i] = f2bf(wk[i]); }
  if (i < CC * CC) { wvb[i] = f2bf(wv[i]); wtb[i] = f2bf(wt[i]); }
  if (i < CC) {
    float s = gmm[i] * rsqrtf(rvar[i] + 1e-5f);
    scale[i] = s;
    bias[i]  = (bt[i] - rmean[i]) * s + bet[i];
  }
}

// ---------------- fused projections, 3-way split (round-11 version) ----------
// y==0: q -> xq (linear);  y==1: kv -> xk (swz) + vt[0:128);  y==2: kv -> vt[128:256)
__global__ __launch_bounds__(256)
void k_proj(const float* __restrict__ q, const float* __restrict__ kv,
            const short* __restrict__ wqb, const short* __restrict__ wkb,
            const short* __restrict__ wvb,
            short* __restrict__ xq, short* __restrict__ xk,
            short* __restrict__ vt) {
  const int lane = threadIdx.x & 63, w = threadIdx.x >> 6;
  const int rowbase = blockIdx.x * 64 + w * 16;
  const int lr = lane & 15, lg = lane >> 4;
  const int y = blockIdx.y;
  if (y == 0) {
    f32x4 acc[4] = {};
#pragma unroll
    for (int kf = 0; kf < 8; ++kf) {
      const float* p = q + (size_t)(rowbase + lr) * CC + kf * 32 + lg * 8;
      float4 x0 = *(const float4*)p, x1 = *(const float4*)(p + 4);
      bf16x8 a;
      a[0] = f2bf(x0.x); a[1] = f2bf(x0.y); a[2] = f2bf(x0.z); a[3] = f2bf(x0.w);
      a[4] = f2bf(x1.x); a[5] = f2bf(x1.y); a[6] = f2bf(x1.z); a[7] = f2bf(x1.w);
#pragma unroll
      for (int nf = 0; nf < 4; ++nf) {
        bf16x8 b = *(const bf16x8*)(wqb + (size_t)(nf * 16 + lr) * CC + kf * 32 + lg * 8);
        acc[nf] = mfma16(a, b, acc[nf]);
      }
    }
#pragma unroll
    for (int nf = 0; nf < 4; ++nf)
#pragma unroll
      for (int r = 0; r < 4; ++r) {
        int row = rowbase + lg * 4 + r;
        xq[(size_t)row * C4 + nf * 16 + lr] = f2bf(acc[nf][r]);
      }
  } else {
    const int cb = (y - 1) * 128;
    f32x4 acck[4] = {};
    f32x4 accv[8] = {};
#pragma unroll
    for (int kf = 0; kf < 8; ++kf) {
      const float* p = kv + (size_t)(rowbase + lr) * CC + kf * 32 + lg * 8;
      float4 x0 = *(const float4*)p, x1 = *(const float4*)(p + 4);
      bf16x8 a;
      a[0] = f2bf(x0.x); a[1] = f2bf(x0.y); a[2] = f2bf(x0.z); a[3] = f2bf(x0.w);
      a[4] = f2bf(x1.x); a[5] = f2bf(x1.y); a[6] = f2bf(x1.z); a[7] = f2bf(x1.w);
      if (y == 1) {
#pragma unroll
        for (int nf = 0; nf < 4; ++nf) {
          bf16x8 b = *(const bf16x8*)(wkb + (size_t)(nf * 16 + lr) * CC + kf * 32 + lg * 8);
          acck[nf] = mfma16(a, b, acck[nf]);
        }
      }
#pragma unroll
      for (int nf = 0; nf < 8; ++nf) {
        bf16x8 b = *(const bf16x8*)(wvb + (size_t)(cb + nf * 16 + lr) * CC + kf * 32 + lg * 8);
        accv[nf] = mfma16(a, b, accv[nf]);
      }
    }
    if (y == 1) {
#pragma unroll
      for (int nf = 0; nf < 4; ++nf)
#pragma unroll
        for (int r = 0; r < 4; ++r) {
          int row = rowbase + lg * 4 + r;
          int d = nf * 16 + lr;
          int off = (((d >> 3) ^ (row & 7)) << 3) + (d & 7);
          xk[(size_t)row * C4 + off] = f2bf(acck[nf][r]);
        }
    }
    {
      int row = rowbase + lg * 4;             // 4 consecutive keys, same 64-tile
      int bidx = row >> 13, kib = row & 8191;
      int tile = kib >> 6, kk = kib & 63;
#pragma unroll
      for (int nf = 0; nf < 8; ++nf) {
        int c = cb + nf * 16 + lr;
        S4 st;
        st.x = f2bf(accv[nf][0]); st.y = f2bf(accv[nf][1]);
        st.z = f2bf(accv[nf][2]); st.w = f2bf(accv[nf][3]);
        int off = (((kk >> 3) ^ (c & 7)) << 3) + (kk & 7);
        *(S4*)(vt + (((size_t)bidx * 128 + tile) * CC + c) * 64 + off) = st;
      }
    }
  }
}

// ---------------- flash attention: 4 waves, 32 q/wave, per-kb streaming ------
// 256 thr, QB=128, KB=64, k-split by gridz, dbuf LDS, m-free softmax,
// ONE __syncthreads() per tile. Per-32-key chunk: QK(kb)->sm(kb)->PV(kb)
// (single s tile = -16 VGPR; QK(kb=1) MFMA overlaps sm/pack(kb=0) VALU).
__global__ __launch_bounds__(256, 2)
void k_attn(const short* __restrict__ xq, const short* __restrict__ xk,
            const short* __restrict__ vt, float* __restrict__ xr,
            short* __restrict__ po, float* __restrict__ pl, int nsplit) {
  __shared__ char Lds[81920];   // 2 x (8KB K + 32KB V)
  const int tid = threadIdx.x;
  const int ln = tid & 63, w = tid >> 6;
  const int qcol = ln & 31, hi = ln >> 5;
  const int b = blockIdx.y, qt = blockIdx.x, kz = blockIdx.z;
  const int kpb = (NK / 64) / nsplit;
  const int kt0 = kz * kpb, kt1 = kt0 + kpb;

  bf16x8 qb[4];
  {
    const short* qrow = xq + (size_t)(b * NQ + qt * 128 + w * 32 + qcol) * C4;
#pragma unroll
    for (int ds = 0; ds < 4; ++ds)
      qb[ds] = *(const bf16x8*)(qrow + ds * 16 + hi * 8);
  }
  f32x16 o[8] = {};
  float lsum = 0.f;

  const char* kgbase = (const char*)(xk + (size_t)b * NK * C4);
  const char* vgbase = (const char*)(vt + (size_t)b * 128 * 16384);

  auto stage = [&](int kt, char* base) {   // per wave: 2 K loads then 8 V loads
    const char* ks = kgbase + (size_t)kt * 8192;
    const char* vs = vgbase + (size_t)kt * 32768;
#pragma unroll
    for (int i = 0; i < 2; ++i)
      gld_lds16(ks + (w * 2 + i) * 1024 + ln * 16, base + (w * 2 + i) * 1024);
#pragma unroll
    for (int i = 0; i < 8; ++i)
      gld_lds16(vs + (w * 8 + i) * 1024 + ln * 16, base + 8192 + (w * 8 + i) * 1024);
  };

  stage(kt0, Lds);
#pragma unroll 1
  for (int t = kt0; t < kt1; ++t) {
    char* cur = Lds + ((t - kt0) & 1) * 40960;
    char* nxt = Lds + ((~(t - kt0)) & 1) * 40960;
    __syncthreads();                      // drain own stage(t) + all t-1 reads
    if (t + 1 < kt1) stage(t + 1, nxt);   // in flight across whole body
#pragma unroll
    for (int kb = 0; kb < 2; ++kb) {
      const int key = kb * 32 + qcol;
      // ---- S^T(kb) = K x Q^T (32 keys)
      f32x16 s = (f32x16)0.f;
      __builtin_amdgcn_s_setprio(1);
#pragma unroll
      for (int ds = 0; ds < 4; ++ds) {
        int cc = ds * 2 + hi;
        bf16x8 ka = *(const bf16x8*)(cur + key * 128 + ((cc ^ (key & 7)) << 4));
        s = mfma32(ka, qb[ds], s);
      }
      __builtin_amdgcn_s_setprio(0);
      // ---- m-free softmax chunk (|S*log2e| bounded; f32 exp2 headroom huge)
      float rs = 0.f;
#pragma unroll
      for (int r = 0; r < 16; ++r) {
        float p = __builtin_amdgcn_exp2f(s[r]);
        s[r] = p; rs += p;
      }
      rs += __shfl_xor(rs, 32);
      lsum += rs;
      // ---- pack 16 f32 -> 2 bf16x8 B-frags via cvt_pk + permlane32_swap
      bf16x8 pb[2];
      {
        unsigned wv[4], uv[4];
#pragma unroll
        for (int j = 0; j < 4; ++j) {
          asm("v_cvt_pk_bf16_f32 %0, %1, %2"
              : "=v"(wv[j]) : "v"(s[4 * j + 0]), "v"(s[4 * j + 1]));
          asm("v_cvt_pk_bf16_f32 %0, %1, %2"
              : "=v"(uv[j]) : "v"(s[4 * j + 2]), "v"(s[4 * j + 3]));
        }
#pragma unroll
        for (int jj = 0; jj < 2; ++jj) {
          uint2v rw = __builtin_amdgcn_permlane32_swap(wv[2 * jj], wv[2 * jj + 1], false, false);
          uint2v ru = __builtin_amdgcn_permlane32_swap(uv[2 * jj], uv[2 * jj + 1], false, false);
          unsigned tmp[4] = { rw[0], ru[0], rw[1], ru[1] };
          bf16x8 t2; __builtin_memcpy(&t2, tmp, 16);
          pb[jj] = t2;
        }
      }
      // ---- O^T += V^T(kb) x P^T(kb)
      __builtin_amdgcn_s_setprio(1);
#pragma unroll
      for (int cb = 0; cb < 8; ++cb) {
        int c = cb * 32 + qcol;
#pragma unroll
        for (int kss = 0; kss < 2; ++kss) {
          int cc = (kb * 2 + kss) * 2 + hi;
          bf16x8 va = *(const bf16x8*)(cur + 8192 + c * 128 + ((cc ^ (c & 7)) << 4));
          o[cb] = mfma32(va, pb[kss], o[cb]);
        }
      }
      __builtin_amdgcn_s_setprio(0);
    }
  }
  __syncthreads();               // all reads done before LDS reuse as scratch

  // ---- epilogue: transpose per-wave via LDS scratch, coalesced stores
  char* tb = Lds + w * 4096;  // 4 KB/wave
  const size_t rb = (size_t)b * NQ + qt * 128 + w * 32;
  if (nsplit == 1) {
    float inv = 1.f / lsum;
#pragma unroll
    for (int cb = 0; cb < 8; ++cb) {
#pragma unroll
      for (int j = 0; j < 4; ++j) {
        f32x4 v;
        v[0] = o[cb][4 * j + 0] * inv; v[1] = o[cb][4 * j + 1] * inv;
        v[2] = o[cb][4 * j + 2] * inv; v[3] = o[cb][4 * j + 3] * inv;
        *(f32x4*)(tb + qcol * 128 + (((2 * j + hi) ^ (qcol & 7)) << 4)) = v;
      }
#pragma unroll
      for (int jr = 0; jr < 4; ++jr) {
        int qr = jr * 8 + (ln >> 3), cc = ln & 7;
        f32x4 v = *(const f32x4*)(tb + qr * 128 + ((cc ^ (qr & 7)) << 4));
        *(f32x4*)(xr + (rb + qr) * CC + cb * 32 + cc * 4) = v;
      }
    }
  } else {
#pragma unroll
    for (int cb = 0; cb < 8; ++cb) {
#pragma unroll
      for (int j = 0; j < 4; ++j) {
        f32x4 v;
        v[0] = o[cb][4 * j + 0]; v[1] = o[cb][4 * j + 1];
        v[2] = o[cb][4 * j + 2]; v[3] = o[cb][4 * j + 3];
        *(f32x4*)(tb + qcol * 128 + (((2 * j + hi) ^ (qcol & 7)) << 4)) = v;
      }
#pragma unroll
      for (int jr = 0; jr < 4; ++jr) {
        int qr = jr * 8 + (ln >> 3), cc = ln & 7;
        f32x4 v = *(const f32x4*)(tb + qr * 128 + ((cc ^ (qr & 7)) << 4));
        S4 sv; sv.x = f2bf(v[0]); sv.y = f2bf(v[1]); sv.z = f2bf(v[2]); sv.w = f2bf(v[3]);
        *(S4*)(po + ((size_t)kz * NROWS + rb + qr) * CC + cb * 32 + cc * 4) = sv;
      }
    }
    if (ln < 32) {
      pl[(size_t)kz * NROWS + rb + qcol] = lsum;
    }
  }
}

// ---------------- epilogue (round-11): combine + relu(BN((q-xr) wt^T)+..)+q --
__global__ __launch_bounds__(256)
void k_epilogue(const float* __restrict__ q, const float* __restrict__ xr,
                const short* __restrict__ po, const float* __restrict__ pl,
                const short* __restrict__ wtb, const float* __restrict__ scale,
                const float* __restrict__ bias, float* __restrict__ out,
                int nsplit) {
  const int lane = threadIdx.x & 63, w = threadIdx.x >> 6;
  const int rowbase = blockIdx.x * 64 + w * 16;
  const int cb = blockIdx.y * 128;
  const int lr = lane & 15, lg = lane >> 4;
  float invL = 1.f;
  if (nsplit > 1) {
    float L = 0.f;
#pragma unroll
    for (int z = 0; z < 4; ++z) L += pl[(size_t)z * NROWS + rowbase + lr];
    invL = 1.f / L;
  }
  f32x4 acc[8] = {};
#pragma unroll
  for (int kf = 0; kf < 8; ++kf) {
    size_t base = (size_t)(rowbase + lr) * CC + kf * 32 + lg * 8;
    float4 q0 = *(const float4*)(q + base), q1 = *(const float4*)(q + base + 4);
    float xv[8];
    if (nsplit > 1) {
#pragma unroll
      for (int j = 0; j < 8; ++j) xv[j] = 0.f;
#pragma unroll
      for (int z = 0; z < 4; ++z) {
        bf16x8 t = *(const bf16x8*)(po + (size_t)z * NROWS * CC + base);
#pragma unroll
        for (int j = 0; j < 8; ++j) xv[j] += bf2f(t[j]);
      }
#pragma unroll
      for (int j = 0; j < 8; ++j) xv[j] *= invL;
    } else {
      float4 r0 = *(const float4*)(xr + base), r1 = *(const float4*)(xr + base + 4);
      xv[0] = r0.x; xv[1] = r0.y; xv[2] = r0.z; xv[3] = r0.w;
      xv[4] = r1.x; xv[5] = r1.y; xv[6] = r1.z; xv[7] = r1.w;
    }
    bf16x8 a;
    a[0] = f2bf(q0.x - xv[0]); a[1] = f2bf(q0.y - xv[1]);
    a[2] = f2bf(q0.z - xv[2]); a[3] = f2bf(q0.w - xv[3]);
    a[4] = f2bf(q1.x - xv[4]); a[5] = f2bf(q1.y - xv[5]);
    a[6] = f2bf(q1.z - xv[6]); a[7] = f2bf(q1.w - xv[7]);
#pragma unroll
    for (int nf = 0; nf < 8; ++nf) {
      bf16x8 b = *(const bf16x8*)(wtb + (size_t)(cb + nf * 16 + lr) * CC + kf * 32 + lg * 8);
      acc[nf] = mfma16(a, b, acc[nf]);
    }
  }
#pragma unroll
  for (int nf = 0; nf < 8; ++nf) {
    int c = cb + nf * 16 + lr;
    float sc = scale[c], bi = bias[c];
#pragma unroll
    for (int r = 0; r < 4; ++r) {
      int row = rowbase + lg * 4 + r;
      float y = acc[nf][r] * sc + bi;
      y = fmaxf(y, 0.f) + q[(size_t)row * CC + c];
      out[(size_t)row * CC + c] = y;
    }
  }
}

// ---------------- launch -----------------------------------------------------
extern "C" void kernel_launch(void* const* d_in, const int* in_sizes, int n_in,
                              void* d_out, int out_size, void* d_ws, size_t ws_size,
                              hipStream_t stream) {
  const float* q     = (const float*)d_in[0];
  const float* kv    = (const float*)d_in[1];
  const float* wq    = (const float*)d_in[2];
  const float* wk    = (const float*)d_in[3];
  const float* wv    = (const float*)d_in[4];
  const float* wt    = (const float*)d_in[5];
  const float* bt    = (const float*)d_in[6];
  const float* gmm   = (const float*)d_in[7];
  const float* bet   = (const float*)d_in[8];
  const float* rmean = (const float*)d_in[9];
  const float* rvar  = (const float*)d_in[10];
  float* out = (float*)d_out;
  char* ws = (char*)d_ws;

  short* wqb  = (short*)(ws + 0);         // 32 KB
  short* wkb  = (short*)(ws + 32768);     // 32 KB
  short* wvb  = (short*)(ws + 65536);     // 128 KB
  short* wtb  = (short*)(ws + 196608);    // 128 KB
  float* scale= (float*)(ws + 327680);    // 1 KB
  float* bias = (float*)(ws + 328704);    // 1 KB
  short* xq   = (short*)(ws + 329728);    // 2 MB
  short* xk   = (short*)(ws + 2426880);   // 2 MB
  short* vt   = (short*)(ws + 4524032);   // 8 MB
  float* xr   = (float*)(ws + 12912640);  // 16 MB
  short* po   = (short*)(ws + 29689856);  // 32 MB (4 x 16384 x 256 bf16)
  float* pl   = (float*)(ws + 63244288);  // 256 KB
  const size_t NEED = 63506432;
  const int nsplit = (ws_size >= NEED) ? 4 : 1;

  k_setup<<<256, 256, 0, stream>>>(wq, wk, wv, wt, bt, gmm, bet, rmean, rvar,
                                   wqb, wkb, wvb, wtb, scale, bias);
  k_proj<<<dim3(256, 3), 256, 0, stream>>>(q, kv, wqb, wkb, wvb, xq, xk, vt);
  k_attn<<<dim3(64, 2, nsplit), 256, 0, stream>>>(xq, xk, vt, xr, po, pl, nsplit);
  k_epilogue<<<dim3(256, 2), 256, 0, stream>>>(q, xr, po, pl, wtb, scale, bias, out, nsplit);
}

// Round 14
// 155.016 us; speedup vs baseline: 1.3202x; 1.3202x over previous
//
#include <hip/hip_runtime.h>
#include <hip/hip_bf16.h>

#define DEVINL __device__ __forceinline__

typedef short bf16x8 __attribute__((ext_vector_type(8)));
typedef float f32x4  __attribute__((ext_vector_type(4)));
typedef float f32x16 __attribute__((ext_vector_type(16)));
typedef unsigned int uint2v __attribute__((ext_vector_type(2)));

struct alignas(8) S4 { short x, y, z, w; };

DEVINL short f2bf(float f) {
  __hip_bfloat16 h = __float2bfloat16(f);
  short s; __builtin_memcpy(&s, &h, 2); return s;
}
DEVINL float bf2f(short s) {
  unsigned u = ((unsigned)(unsigned short)s) << 16;
  float f; __builtin_memcpy(&f, &u, 4); return f;
}

DEVINL f32x4 mfma16(bf16x8 a, bf16x8 b, f32x4 c) {
  return __builtin_amdgcn_mfma_f32_16x16x32_bf16(a, b, c, 0, 0, 0);
}
DEVINL f32x16 mfma32(bf16x8 a, bf16x8 b, f32x16 c) {
  return __builtin_amdgcn_mfma_f32_32x32x16_bf16(a, b, c, 0, 0, 0);
}

// async global->LDS, 16B per lane; LDS dest is wave-uniform base (+lane*16 by HW)
DEVINL void gld_lds16(const void* gptr, void* lptr) {
  __builtin_amdgcn_global_load_lds(
      (const __attribute__((address_space(1))) unsigned int*)gptr,
      (__attribute__((address_space(3))) unsigned int*)lptr, 16, 0, 0);
}

#define CC 256
#define C4 64
#define BB 2
#define NQ 8192
#define NK 8192
#define NROWS (BB * NQ)
#define LOG2E 1.44269504f

// ---------------- setup: weights -> bf16 (wq pre-scaled by log2e), BN fold ---
__global__ void k_setup(const float* __restrict__ wq, const float* __restrict__ wk,
                        const float* __restrict__ wv, const float* __restrict__ wt,
                        const float* __restrict__ bt, const float* __restrict__ gmm,
                        const float* __restrict__ bet, const float* __restrict__ rmean,
                        const float* __restrict__ rvar,
                        short* __restrict__ wqb, short* __restrict__ wkb,
                        short* __restrict__ wvb, short* __restrict__ wtb,
                        float* __restrict__ scale, float* __restrict__ bias) {
  int i = blockIdx.x * 256 + threadIdx.x;
  if (i < C4 * CC) { wqb[i] = f2bf(wq[i] * LOG2E); wkb[i] = f2bf(wk[i]); }
  if (i < CC * CC) { wvb[i] = f2bf(wv[i]); wtb[i] = f2bf(wt[i]); }
  if (i < CC) {
    float s = gmm[i] * rsqrtf(rvar[i] + 1e-5f);
    scale[i] = s;
    bias[i]  = (bt[i] - rmean[i]) * s + bet[i];
  }
}

// ---------------- fused projections, 3-way split -----------------------------
// y==0: q -> xq (linear);  y==1: kv -> xk (swz) + vt[0:128);  y==2: kv -> vt[128:256)
// 16 rows/wave, 64 rows/block, grid (256, 3) = 768 blocks (3/CU)
__global__ __launch_bounds__(256)
void k_proj(const float* __restrict__ q, const float* __restrict__ kv,
            const short* __restrict__ wqb, const short* __restrict__ wkb,
            const short* __restrict__ wvb,
            short* __restrict__ xq, short* __restrict__ xk,
            short* __restrict__ vt) {
  const int lane = threadIdx.x & 63, w = threadIdx.x >> 6;
  const int rowbase = blockIdx.x * 64 + w * 16;
  const int lr = lane & 15, lg = lane >> 4;
  const int y = blockIdx.y;
  if (y == 0) {
    f32x4 acc[4] = {};
#pragma unroll
    for (int kf = 0; kf < 8; ++kf) {
      const float* p = q + (size_t)(rowbase + lr) * CC + kf * 32 + lg * 8;
      float4 x0 = *(const float4*)p, x1 = *(const float4*)(p + 4);
      bf16x8 a;
      a[0] = f2bf(x0.x); a[1] = f2bf(x0.y); a[2] = f2bf(x0.z); a[3] = f2bf(x0.w);
      a[4] = f2bf(x1.x); a[5] = f2bf(x1.y); a[6] = f2bf(x1.z); a[7] = f2bf(x1.w);
#pragma unroll
      for (int nf = 0; nf < 4; ++nf) {
        bf16x8 b = *(const bf16x8*)(wqb + (size_t)(nf * 16 + lr) * CC + kf * 32 + lg * 8);
        acc[nf] = mfma16(a, b, acc[nf]);
      }
    }
#pragma unroll
    for (int nf = 0; nf < 4; ++nf)
#pragma unroll
      for (int r = 0; r < 4; ++r) {
        int row = rowbase + lg * 4 + r;
        xq[(size_t)row * C4 + nf * 16 + lr] = f2bf(acc[nf][r]);
      }
  } else {
    const int cb = (y - 1) * 128;
    f32x4 acck[4] = {};
    f32x4 accv[8] = {};
#pragma unroll
    for (int kf = 0; kf < 8; ++kf) {
      const float* p = kv + (size_t)(rowbase + lr) * CC + kf * 32 + lg * 8;
      float4 x0 = *(const float4*)p, x1 = *(const float4*)(p + 4);
      bf16x8 a;
      a[0] = f2bf(x0.x); a[1] = f2bf(x0.y); a[2] = f2bf(x0.z); a[3] = f2bf(x0.w);
      a[4] = f2bf(x1.x); a[5] = f2bf(x1.y); a[6] = f2bf(x1.z); a[7] = f2bf(x1.w);
      if (y == 1) {
#pragma unroll
        for (int nf = 0; nf < 4; ++nf) {
          bf16x8 b = *(const bf16x8*)(wkb + (size_t)(nf * 16 + lr) * CC + kf * 32 + lg * 8);
          acck[nf] = mfma16(a, b, acck[nf]);
        }
      }
#pragma unroll
      for (int nf = 0; nf < 8; ++nf) {
        bf16x8 b = *(const bf16x8*)(wvb + (size_t)(cb + nf * 16 + lr) * CC + kf * 32 + lg * 8);
        accv[nf] = mfma16(a, b, accv[nf]);
      }
    }
    if (y == 1) {
#pragma unroll
      for (int nf = 0; nf < 4; ++nf)
#pragma unroll
        for (int r = 0; r < 4; ++r) {
          int row = rowbase + lg * 4 + r;
          int d = nf * 16 + lr;
          int off = (((d >> 3) ^ (row & 7)) << 3) + (d & 7);
          xk[(size_t)row * C4 + off] = f2bf(acck[nf][r]);
        }
    }
    {
      int row = rowbase + lg * 4;             // 4 consecutive keys, same 64-tile
      int bidx = row >> 13, kib = row & 8191;
      int tile = kib >> 6, kk = kib & 63;
#pragma unroll
      for (int nf = 0; nf < 8; ++nf) {
        int c = cb + nf * 16 + lr;
        S4 st;
        st.x = f2bf(accv[nf][0]); st.y = f2bf(accv[nf][1]);
        st.z = f2bf(accv[nf][2]); st.w = f2bf(accv[nf][3]);
        int off = (((kk >> 3) ^ (c & 7)) << 3) + (kk & 7);
        *(S4*)(vt + (((size_t)bidx * 128 + tile) * CC + c) * 64 + off) = st;
      }
    }
  }
}

// ---------------- flash attention: round-11 (best verified: 93us, no spill) --
// 256 thr (4 waves), 32 q/wave, QB=128, KB=64, k-split by gridz, dbuf LDS,
// m-free softmax. Sync = ONE __syncthreads() per tile (compiler-fenced drain).
__global__ __launch_bounds__(256, 2)
void k_attn(const short* __restrict__ xq, const short* __restrict__ xk,
            const short* __restrict__ vt, float* __restrict__ xr,
            short* __restrict__ po, float* __restrict__ pl, int nsplit) {
  __shared__ char Lds[81920];   // 2 x (8KB K + 32KB V)
  const int tid = threadIdx.x;
  const int ln = tid & 63, w = tid >> 6;
  const int qcol = ln & 31, hi = ln >> 5;
  const int b = blockIdx.y, qt = blockIdx.x, kz = blockIdx.z;
  const int kpb = (NK / 64) / nsplit;
  const int kt0 = kz * kpb, kt1 = kt0 + kpb;

  bf16x8 qb[4];
  {
    const short* qrow = xq + (size_t)(b * NQ + qt * 128 + w * 32 + qcol) * C4;
#pragma unroll
    for (int ds = 0; ds < 4; ++ds)
      qb[ds] = *(const bf16x8*)(qrow + ds * 16 + hi * 8);
  }
  f32x16 o[8] = {};
  float lsum = 0.f;

  const char* kgbase = (const char*)(xk + (size_t)b * NK * C4);
  const char* vgbase = (const char*)(vt + (size_t)b * 128 * 16384);

  auto stage = [&](int kt, char* base) {   // per wave: 2 K loads then 8 V loads
    const char* ks = kgbase + (size_t)kt * 8192;
    const char* vs = vgbase + (size_t)kt * 32768;
#pragma unroll
    for (int i = 0; i < 2; ++i)
      gld_lds16(ks + (w * 2 + i) * 1024 + ln * 16, base + (w * 2 + i) * 1024);
#pragma unroll
    for (int i = 0; i < 8; ++i)
      gld_lds16(vs + (w * 8 + i) * 1024 + ln * 16, base + 8192 + (w * 8 + i) * 1024);
  };

  f32x16 s[2];
  bf16x8 pb[4];

  stage(kt0, Lds);
#pragma unroll 1
  for (int t = kt0; t < kt1; ++t) {
    char* cur = Lds + ((t - kt0) & 1) * 40960;
    char* nxt = Lds + ((~(t - kt0)) & 1) * 40960;
    __syncthreads();                      // drain own stage(t) + all t-1 reads
    if (t + 1 < kt1) stage(t + 1, nxt);   // in flight across whole body
    // ---- S^T = K x Q^T : lane holds 32 key-values for q = qcol
    s[0] = (f32x16)0.f; s[1] = (f32x16)0.f;
    __builtin_amdgcn_s_setprio(1);
#pragma unroll
    for (int kb = 0; kb < 2; ++kb) {
      int key = kb * 32 + qcol;
#pragma unroll
      for (int ds = 0; ds < 4; ++ds) {
        int cc = ds * 2 + hi;
        bf16x8 ka = *(const bf16x8*)(cur + key * 128 + ((cc ^ (key & 7)) << 4));
        s[kb] = mfma32(ka, qb[ds], s[kb]);
      }
    }
    __builtin_amdgcn_s_setprio(0);
    // ---- m-free softmax (|S*log2e| bounded; f32 exp2 has huge headroom)
    float rs = 0.f;
#pragma unroll
    for (int kb = 0; kb < 2; ++kb)
#pragma unroll
      for (int r = 0; r < 16; ++r) {
        float p = __builtin_amdgcn_exp2f(s[kb][r]);
        s[kb][r] = p; rs += p;
      }
    rs += __shfl_xor(rs, 32);
    lsum += rs;
    // ---- P -> bf16 B-frags via cvt_pk + permlane32_swap (no LDS)
#pragma unroll
    for (int kb = 0; kb < 2; ++kb) {
      unsigned wv[4], uv[4];
#pragma unroll
      for (int j = 0; j < 4; ++j) {
        asm("v_cvt_pk_bf16_f32 %0, %1, %2"
            : "=v"(wv[j]) : "v"(s[kb][4 * j + 0]), "v"(s[kb][4 * j + 1]));
        asm("v_cvt_pk_bf16_f32 %0, %1, %2"
            : "=v"(uv[j]) : "v"(s[kb][4 * j + 2]), "v"(s[kb][4 * j + 3]));
      }
#pragma unroll
      for (int jj = 0; jj < 2; ++jj) {
        uint2v rw = __builtin_amdgcn_permlane32_swap(wv[2 * jj], wv[2 * jj + 1], false, false);
        uint2v ru = __builtin_amdgcn_permlane32_swap(uv[2 * jj], uv[2 * jj + 1], false, false);
        unsigned tmp[4] = { rw[0], ru[0], rw[1], ru[1] };
        bf16x8 t2; __builtin_memcpy(&t2, tmp, 16);
        pb[kb * 2 + jj] = t2;
      }
    }
    // ---- O^T += V^T x P^T
    __builtin_amdgcn_s_setprio(1);
#pragma unroll
    for (int cb = 0; cb < 8; ++cb) {
      int c = cb * 32 + qcol;
#pragma unroll
      for (int ks = 0; ks < 4; ++ks) {
        int cc = ks * 2 + hi;
        bf16x8 va = *(const bf16x8*)(cur + 8192 + c * 128 + ((cc ^ (c & 7)) << 4));
        o[cb] = mfma32(va, pb[ks], o[cb]);
      }
    }
    __builtin_amdgcn_s_setprio(0);
  }
  __syncthreads();               // all reads done before LDS reuse as scratch

  // ---- epilogue: transpose per-wave via LDS scratch, coalesced stores
  char* tb = Lds + w * 4096;  // 4 KB/wave
  const size_t rb = (size_t)b * NQ + qt * 128 + w * 32;
  if (nsplit == 1) {
    float inv = 1.f / lsum;
#pragma unroll
    for (int cb = 0; cb < 8; ++cb) {
#pragma unroll
      for (int j = 0; j < 4; ++j) {
        f32x4 v;
        v[0] = o[cb][4 * j + 0] * inv; v[1] = o[cb][4 * j + 1] * inv;
        v[2] = o[cb][4 * j + 2] * inv; v[3] = o[cb][4 * j + 3] * inv;
        *(f32x4*)(tb + qcol * 128 + (((2 * j + hi) ^ (qcol & 7)) << 4)) = v;
      }
#pragma unroll
      for (int jr = 0; jr < 4; ++jr) {
        int qr = jr * 8 + (ln >> 3), cc = ln & 7;
        f32x4 v = *(const f32x4*)(tb + qr * 128 + ((cc ^ (qr & 7)) << 4));
        *(f32x4*)(xr + (rb + qr) * CC + cb * 32 + cc * 4) = v;
      }
    }
  } else {
#pragma unroll
    for (int cb = 0; cb < 8; ++cb) {
#pragma unroll
      for (int j = 0; j < 4; ++j) {
        f32x4 v;
        v[0] = o[cb][4 * j + 0]; v[1] = o[cb][4 * j + 1];
        v[2] = o[cb][4 * j + 2]; v[3] = o[cb][4 * j + 3];
        *(f32x4*)(tb + qcol * 128 + (((2 * j + hi) ^ (qcol & 7)) << 4)) = v;
      }
#pragma unroll
      for (int jr = 0; jr < 4; ++jr) {
        int qr = jr * 8 + (ln >> 3), cc = ln & 7;
        f32x4 v = *(const f32x4*)(tb + qr * 128 + ((cc ^ (qr & 7)) << 4));
        S4 sv; sv.x = f2bf(v[0]); sv.y = f2bf(v[1]); sv.z = f2bf(v[2]); sv.w = f2bf(v[3]);
        *(S4*)(po + ((size_t)kz * NROWS + rb + qr) * CC + cb * 32 + cc * 4) = sv;
      }
    }
    if (ln < 32) {
      pl[(size_t)kz * NROWS + rb + qcol] = lsum;
    }
  }
}

// ---------------- epilogue: combine partials + relu(BN((q-xr) wt^T)+..) + q --
__global__ __launch_bounds__(256)
void k_epilogue(const float* __restrict__ q, const float* __restrict__ xr,
                const short* __restrict__ po, const float* __restrict__ pl,
                const short* __restrict__ wtb, const float* __restrict__ scale,
                const float* __restrict__ bias, float* __restrict__ out,
                int nsplit) {
  const int lane = threadIdx.x & 63, w = threadIdx.x >> 6;
  const int rowbase = blockIdx.x * 64 + w * 16;
  const int cb = blockIdx.y * 128;
  const int lr = lane & 15, lg = lane >> 4;
  float invL = 1.f;
  if (nsplit > 1) {
    float L = 0.f;
#pragma unroll
    for (int z = 0; z < 4; ++z) L += pl[(size_t)z * NROWS + rowbase + lr];
    invL = 1.f / L;
  }
  f32x4 acc[8] = {};
#pragma unroll
  for (int kf = 0; kf < 8; ++kf) {
    size_t base = (size_t)(rowbase + lr) * CC + kf * 32 + lg * 8;
    float4 q0 = *(const float4*)(q + base), q1 = *(const float4*)(q + base + 4);
    float xv[8];
    if (nsplit > 1) {
#pragma unroll
      for (int j = 0; j < 8; ++j) xv[j] = 0.f;
#pragma unroll
      for (int z = 0; z < 4; ++z) {
        bf16x8 t = *(const bf16x8*)(po + (size_t)z * NROWS * CC + base);
#pragma unroll
        for (int j = 0; j < 8; ++j) xv[j] += bf2f(t[j]);
      }
#pragma unroll
      for (int j = 0; j < 8; ++j) xv[j] *= invL;
    } else {
      float4 r0 = *(const float4*)(xr + base), r1 = *(const float4*)(xr + base + 4);
      xv[0] = r0.x; xv[1] = r0.y; xv[2] = r0.z; xv[3] = r0.w;
      xv[4] = r1.x; xv[5] = r1.y; xv[6] = r1.z; xv[7] = r1.w;
    }
    bf16x8 a;
    a[0] = f2bf(q0.x - xv[0]); a[1] = f2bf(q0.y - xv[1]);
    a[2] = f2bf(q0.z - xv[2]); a[3] = f2bf(q0.w - xv[3]);
    a[4] = f2bf(q1.x - xv[4]); a[5] = f2bf(q1.y - xv[5]);
    a[6] = f2bf(q1.z - xv[6]); a[7] = f2bf(q1.w - xv[7]);
#pragma unroll
    for (int nf = 0; nf < 8; ++nf) {
      bf16x8 b = *(const bf16x8*)(wtb + (size_t)(cb + nf * 16 + lr) * CC + kf * 32 + lg * 8);
      acc[nf] = mfma16(a, b, acc[nf]);
    }
  }
#pragma unroll
  for (int nf = 0; nf < 8; ++nf) {
    int c = cb + nf * 16 + lr;
    float sc = scale[c], bi = bias[c];
#pragma unroll
    for (int r = 0; r < 4; ++r) {
      int row = rowbase + lg * 4 + r;
      float y = acc[nf][r] * sc + bi;
      y = fmaxf(y, 0.f) + q[(size_t)row * CC + c];
      out[(size_t)row * CC + c] = y;
    }
  }
}

// ---------------- launch -----------------------------------------------------
extern "C" void kernel_launch(void* const* d_in, const int* in_sizes, int n_in,
                              void* d_out, int out_size, void* d_ws, size_t ws_size,
                              hipStream_t stream) {
  const float* q     = (const float*)d_in[0];
  const float* kv    = (const float*)d_in[1];
  const float* wq    = (const float*)d_in[2];
  const float* wk    = (const float*)d_in[3];
  const float* wv    = (const float*)d_in[4];
  const float* wt    = (const float*)d_in[5];
  const float* bt    = (const float*)d_in[6];
  const float* gmm   = (const float*)d_in[7];
  const float* bet   = (const float*)d_in[8];
  const float* rmean = (const float*)d_in[9];
  const float* rvar  = (const float*)d_in[10];
  float* out = (float*)d_out;
  char* ws = (char*)d_ws;

  short* wqb  = (short*)(ws + 0);         // 32 KB
  short* wkb  = (short*)(ws + 32768);     // 32 KB
  short* wvb  = (short*)(ws + 65536);     // 128 KB
  short* wtb  = (short*)(ws + 196608);    // 128 KB
  float* scale= (float*)(ws + 327680);    // 1 KB
  float* bias = (float*)(ws + 328704);    // 1 KB
  short* xq   = (short*)(ws + 329728);    // 2 MB
  short* xk   = (short*)(ws + 2426880);   // 2 MB
  short* vt   = (short*)(ws + 4524032);   // 8 MB
  float* xr   = (float*)(ws + 12912640);  // 16 MB
  short* po   = (short*)(ws + 29689856);  // 32 MB (4 x 16384 x 256 bf16)
  float* pl   = (float*)(ws + 63244288);  // 256 KB
  const size_t NEED = 63506432;
  const int nsplit = (ws_size >= NEED) ? 4 : 1;

  k_setup<<<256, 256, 0, stream>>>(wq, wk, wv, wt, bt, gmm, bet, rmean, rvar,
                                   wqb, wkb, wvb, wtb, scale, bias);
  k_proj<<<dim3(256, 3), 256, 0, stream>>>(q, kv, wqb, wkb, wvb, xq, xk, vt);
  k_attn<<<dim3(64, 2, nsplit), 256, 0, stream>>>(xq, xk, vt, xr, po, pl, nsplit);
  k_epilogue<<<dim3(256, 2), 256, 0, stream>>>(q, xr, po, pl, wtb, scale, bias, out, nsplit);
}

// Round 15
// 153.619 us; speedup vs baseline: 1.3322x; 1.0091x over previous
//
#include <hip/hip_runtime.h>
#include <hip/hip_bf16.h>

#define DEVINL __device__ __forceinline__

typedef short bf16x8 __attribute__((ext_vector_type(8)));
typedef float f32x4  __attribute__((ext_vector_type(4)));
typedef float f32x16 __attribute__((ext_vector_type(16)));
typedef unsigned int uint2v __attribute__((ext_vector_type(2)));

struct alignas(8) S4 { short x, y, z, w; };

DEVINL short f2bf(float f) {
  __hip_bfloat16 h = __float2bfloat16(f);
  short s; __builtin_memcpy(&s, &h, 2); return s;
}
DEVINL float bf2f(short s) {
  unsigned u = ((unsigned)(unsigned short)s) << 16;
  float f; __builtin_memcpy(&f, &u, 4); return f;
}

DEVINL f32x4 mfma16(bf16x8 a, bf16x8 b, f32x4 c) {
  return __builtin_amdgcn_mfma_f32_16x16x32_bf16(a, b, c, 0, 0, 0);
}
DEVINL f32x16 mfma32(bf16x8 a, bf16x8 b, f32x16 c) {
  return __builtin_amdgcn_mfma_f32_32x32x16_bf16(a, b, c, 0, 0, 0);
}

// async global->LDS, 16B per lane; LDS dest is wave-uniform base (+lane*16 by HW)
DEVINL void gld_lds16(const void* gptr, void* lptr) {
  __builtin_amdgcn_global_load_lds(
      (const __attribute__((address_space(1))) unsigned int*)gptr,
      (__attribute__((address_space(3))) unsigned int*)lptr, 16, 0, 0);
}

#define CC 256
#define C4 64
#define BB 2
#define NQ 8192
#define NK 8192
#define NROWS (BB * NQ)
#define LOG2E 1.44269504f

// ---------------- setup: weights -> bf16 (wq pre-scaled by log2e), BN fold ---
__global__ void k_setup(const float* __restrict__ wq, const float* __restrict__ wk,
                        const float* __restrict__ wv, const float* __restrict__ wt,
                        const float* __restrict__ bt, const float* __restrict__ gmm,
                        const float* __restrict__ bet, const float* __restrict__ rmean,
                        const float* __restrict__ rvar,
                        short* __restrict__ wqb, short* __restrict__ wkb,
                        short* __restrict__ wvb, short* __restrict__ wtb,
                        float* __restrict__ scale, float* __restrict__ bias) {
  int i = blockIdx.x * 256 + threadIdx.x;
  if (i < C4 * CC) { wqb[i] = f2bf(wq[i] * LOG2E); wkb[i] = f2bf(wk[i]); }
  if (i < CC * CC) { wvb[i] = f2bf(wv[i]); wtb[i] = f2bf(wt[i]); }
  if (i < CC) {
    float s = gmm[i] * rsqrtf(rvar[i] + 1e-5f);
    scale[i] = s;
    bias[i]  = (bt[i] - rmean[i]) * s + bet[i];
  }
}

// ---------------- fused projections, balanced 3-way split --------------------
// y==0: q -> xq (linear);  y==1: kv -> xk (swz) + vt[0:96) (10 frag-accs);
// y==2: kv -> vt[96:256) (10 frag-accs). grid (256, 3) = 768 blocks
__global__ __launch_bounds__(256)
void k_proj(const float* __restrict__ q, const float* __restrict__ kv,
            const short* __restrict__ wqb, const short* __restrict__ wkb,
            const short* __restrict__ wvb,
            short* __restrict__ xq, short* __restrict__ xk,
            short* __restrict__ vt) {
  const int lane = threadIdx.x & 63, w = threadIdx.x >> 6;
  const int rowbase = blockIdx.x * 64 + w * 16;
  const int lr = lane & 15, lg = lane >> 4;
  const int y = blockIdx.y;
  if (y == 0) {
    f32x4 acc[4] = {};
#pragma unroll
    for (int kf = 0; kf < 8; ++kf) {
      const float* p = q + (size_t)(rowbase + lr) * CC + kf * 32 + lg * 8;
      float4 x0 = *(const float4*)p, x1 = *(const float4*)(p + 4);
      bf16x8 a;
      a[0] = f2bf(x0.x); a[1] = f2bf(x0.y); a[2] = f2bf(x0.z); a[3] = f2bf(x0.w);
      a[4] = f2bf(x1.x); a[5] = f2bf(x1.y); a[6] = f2bf(x1.z); a[7] = f2bf(x1.w);
#pragma unroll
      for (int nf = 0; nf < 4; ++nf) {
        bf16x8 b = *(const bf16x8*)(wqb + (size_t)(nf * 16 + lr) * CC + kf * 32 + lg * 8);
        acc[nf] = mfma16(a, b, acc[nf]);
      }
    }
#pragma unroll
    for (int nf = 0; nf < 4; ++nf)
#pragma unroll
      for (int r = 0; r < 4; ++r) {
        int row = rowbase + lg * 4 + r;
        xq[(size_t)row * C4 + nf * 16 + lr] = f2bf(acc[nf][r]);
      }
  } else if (y == 1) {
    // ---- kv -> xk (swizzled) + vt cols [0,96)
    f32x4 acck[4] = {};
    f32x4 accv[6] = {};
#pragma unroll
    for (int kf = 0; kf < 8; ++kf) {
      const float* p = kv + (size_t)(rowbase + lr) * CC + kf * 32 + lg * 8;
      float4 x0 = *(const float4*)p, x1 = *(const float4*)(p + 4);
      bf16x8 a;
      a[0] = f2bf(x0.x); a[1] = f2bf(x0.y); a[2] = f2bf(x0.z); a[3] = f2bf(x0.w);
      a[4] = f2bf(x1.x); a[5] = f2bf(x1.y); a[6] = f2bf(x1.z); a[7] = f2bf(x1.w);
#pragma unroll
      for (int nf = 0; nf < 4; ++nf) {
        bf16x8 b = *(const bf16x8*)(wkb + (size_t)(nf * 16 + lr) * CC + kf * 32 + lg * 8);
        acck[nf] = mfma16(a, b, acck[nf]);
      }
#pragma unroll
      for (int nf = 0; nf < 6; ++nf) {
        bf16x8 b = *(const bf16x8*)(wvb + (size_t)(nf * 16 + lr) * CC + kf * 32 + lg * 8);
        accv[nf] = mfma16(a, b, accv[nf]);
      }
    }
#pragma unroll
    for (int nf = 0; nf < 4; ++nf)
#pragma unroll
      for (int r = 0; r < 4; ++r) {
        int row = rowbase + lg * 4 + r;
        int d = nf * 16 + lr;
        int off = (((d >> 3) ^ (row & 7)) << 3) + (d & 7);
        xk[(size_t)row * C4 + off] = f2bf(acck[nf][r]);
      }
    {
      int row = rowbase + lg * 4;             // 4 consecutive keys, same 64-tile
      int bidx = row >> 13, kib = row & 8191;
      int tile = kib >> 6, kk = kib & 63;
#pragma unroll
      for (int nf = 0; nf < 6; ++nf) {
        int c = nf * 16 + lr;
        S4 st;
        st.x = f2bf(accv[nf][0]); st.y = f2bf(accv[nf][1]);
        st.z = f2bf(accv[nf][2]); st.w = f2bf(accv[nf][3]);
        int off = (((kk >> 3) ^ (c & 7)) << 3) + (kk & 7);
        *(S4*)(vt + (((size_t)bidx * 128 + tile) * CC + c) * 64 + off) = st;
      }
    }
  } else {
    // ---- kv -> vt cols [96,256)
    f32x4 accv[10] = {};
#pragma unroll
    for (int kf = 0; kf < 8; ++kf) {
      const float* p = kv + (size_t)(rowbase + lr) * CC + kf * 32 + lg * 8;
      float4 x0 = *(const float4*)p, x1 = *(const float4*)(p + 4);
      bf16x8 a;
      a[0] = f2bf(x0.x); a[1] = f2bf(x0.y); a[2] = f2bf(x0.z); a[3] = f2bf(x0.w);
      a[4] = f2bf(x1.x); a[5] = f2bf(x1.y); a[6] = f2bf(x1.z); a[7] = f2bf(x1.w);
#pragma unroll
      for (int nf = 0; nf < 10; ++nf) {
        bf16x8 b = *(const bf16x8*)(wvb + (size_t)(96 + nf * 16 + lr) * CC + kf * 32 + lg * 8);
        accv[nf] = mfma16(a, b, accv[nf]);
      }
    }
    {
      int row = rowbase + lg * 4;             // 4 consecutive keys, same 64-tile
      int bidx = row >> 13, kib = row & 8191;
      int tile = kib >> 6, kk = kib & 63;
#pragma unroll
      for (int nf = 0; nf < 10; ++nf) {
        int c = 96 + nf * 16 + lr;
        S4 st;
        st.x = f2bf(accv[nf][0]); st.y = f2bf(accv[nf][1]);
        st.z = f2bf(accv[nf][2]); st.w = f2bf(accv[nf][3]);
        int off = (((kk >> 3) ^ (c & 7)) << 3) + (kk & 7);
        *(S4*)(vt + (((size_t)bidx * 128 + tile) * CC + c) * 64 + off) = st;
      }
    }
  }
}

// ---------------- flash attention: round-11 (best verified: 93us, no spill) --
// 256 thr (4 waves), 32 q/wave, QB=128, KB=64, k-split by gridz, dbuf LDS,
// m-free softmax. Sync = ONE __syncthreads() per tile (compiler-fenced drain).
__global__ __launch_bounds__(256, 2)
void k_attn(const short* __restrict__ xq, const short* __restrict__ xk,
            const short* __restrict__ vt, float* __restrict__ xr,
            short* __restrict__ po, float* __restrict__ pl, int nsplit) {
  __shared__ char Lds[81920];   // 2 x (8KB K + 32KB V)
  const int tid = threadIdx.x;
  const int ln = tid & 63, w = tid >> 6;
  const int qcol = ln & 31, hi = ln >> 5;
  const int b = blockIdx.y, qt = blockIdx.x, kz = blockIdx.z;
  const int kpb = (NK / 64) / nsplit;
  const int kt0 = kz * kpb, kt1 = kt0 + kpb;

  bf16x8 qb[4];
  {
    const short* qrow = xq + (size_t)(b * NQ + qt * 128 + w * 32 + qcol) * C4;
#pragma unroll
    for (int ds = 0; ds < 4; ++ds)
      qb[ds] = *(const bf16x8*)(qrow + ds * 16 + hi * 8);
  }
  f32x16 o[8] = {};
  float lsum = 0.f;

  const char* kgbase = (const char*)(xk + (size_t)b * NK * C4);
  const char* vgbase = (const char*)(vt + (size_t)b * 128 * 16384);

  auto stage = [&](int kt, char* base) {   // per wave: 2 K loads then 8 V loads
    const char* ks = kgbase + (size_t)kt * 8192;
    const char* vs = vgbase + (size_t)kt * 32768;
#pragma unroll
    for (int i = 0; i < 2; ++i)
      gld_lds16(ks + (w * 2 + i) * 1024 + ln * 16, base + (w * 2 + i) * 1024);
#pragma unroll
    for (int i = 0; i < 8; ++i)
      gld_lds16(vs + (w * 8 + i) * 1024 + ln * 16, base + 8192 + (w * 8 + i) * 1024);
  };

  f32x16 s[2];
  bf16x8 pb[4];

  stage(kt0, Lds);
#pragma unroll 1
  for (int t = kt0; t < kt1; ++t) {
    char* cur = Lds + ((t - kt0) & 1) * 40960;
    char* nxt = Lds + ((~(t - kt0)) & 1) * 40960;
    __syncthreads();                      // drain own stage(t) + all t-1 reads
    if (t + 1 < kt1) stage(t + 1, nxt);   // in flight across whole body
    // ---- S^T = K x Q^T : lane holds 32 key-values for q = qcol
    s[0] = (f32x16)0.f; s[1] = (f32x16)0.f;
    __builtin_amdgcn_s_setprio(1);
#pragma unroll
    for (int kb = 0; kb < 2; ++kb) {
      int key = kb * 32 + qcol;
#pragma unroll
      for (int ds = 0; ds < 4; ++ds) {
        int cc = ds * 2 + hi;
        bf16x8 ka = *(const bf16x8*)(cur + key * 128 + ((cc ^ (key & 7)) << 4));
        s[kb] = mfma32(ka, qb[ds], s[kb]);
      }
    }
    __builtin_amdgcn_s_setprio(0);
    // ---- m-free softmax (|S*log2e| bounded; f32 exp2 has huge headroom)
    float rs = 0.f;
#pragma unroll
    for (int kb = 0; kb < 2; ++kb)
#pragma unroll
      for (int r = 0; r < 16; ++r) {
        float p = __builtin_amdgcn_exp2f(s[kb][r]);
        s[kb][r] = p; rs += p;
      }
    rs += __shfl_xor(rs, 32);
    lsum += rs;
    // ---- P -> bf16 B-frags via cvt_pk + permlane32_swap (no LDS)
#pragma unroll
    for (int kb = 0; kb < 2; ++kb) {
      unsigned wv[4], uv[4];
#pragma unroll
      for (int j = 0; j < 4; ++j) {
        asm("v_cvt_pk_bf16_f32 %0, %1, %2"
            : "=v"(wv[j]) : "v"(s[kb][4 * j + 0]), "v"(s[kb][4 * j + 1]));
        asm("v_cvt_pk_bf16_f32 %0, %1, %2"
            : "=v"(uv[j]) : "v"(s[kb][4 * j + 2]), "v"(s[kb][4 * j + 3]));
      }
#pragma unroll
      for (int jj = 0; jj < 2; ++jj) {
        uint2v rw = __builtin_amdgcn_permlane32_swap(wv[2 * jj], wv[2 * jj + 1], false, false);
        uint2v ru = __builtin_amdgcn_permlane32_swap(uv[2 * jj], uv[2 * jj + 1], false, false);
        unsigned tmp[4] = { rw[0], ru[0], rw[1], ru[1] };
        bf16x8 t2; __builtin_memcpy(&t2, tmp, 16);
        pb[kb * 2 + jj] = t2;
      }
    }
    // ---- O^T += V^T x P^T
    __builtin_amdgcn_s_setprio(1);
#pragma unroll
    for (int cb = 0; cb < 8; ++cb) {
      int c = cb * 32 + qcol;
#pragma unroll
      for (int ks = 0; ks < 4; ++ks) {
        int cc = ks * 2 + hi;
        bf16x8 va = *(const bf16x8*)(cur + 8192 + c * 128 + ((cc ^ (c & 7)) << 4));
        o[cb] = mfma32(va, pb[ks], o[cb]);
      }
    }
    __builtin_amdgcn_s_setprio(0);
  }
  __syncthreads();               // all reads done before LDS reuse as scratch

  // ---- epilogue: transpose per-wave via LDS scratch, coalesced stores
  char* tb = Lds + w * 4096;  // 4 KB/wave
  const size_t rb = (size_t)b * NQ + qt * 128 + w * 32;
  if (nsplit == 1) {
    float inv = 1.f / lsum;
#pragma unroll
    for (int cb = 0; cb < 8; ++cb) {
#pragma unroll
      for (int j = 0; j < 4; ++j) {
        f32x4 v;
        v[0] = o[cb][4 * j + 0] * inv; v[1] = o[cb][4 * j + 1] * inv;
        v[2] = o[cb][4 * j + 2] * inv; v[3] = o[cb][4 * j + 3] * inv;
        *(f32x4*)(tb + qcol * 128 + (((2 * j + hi) ^ (qcol & 7)) << 4)) = v;
      }
#pragma unroll
      for (int jr = 0; jr < 4; ++jr) {
        int qr = jr * 8 + (ln >> 3), cc = ln & 7;
        f32x4 v = *(const f32x4*)(tb + qr * 128 + ((cc ^ (qr & 7)) << 4));
        *(f32x4*)(xr + (rb + qr) * CC + cb * 32 + cc * 4) = v;
      }
    }
  } else {
#pragma unroll
    for (int cb = 0; cb < 8; ++cb) {
#pragma unroll
      for (int j = 0; j < 4; ++j) {
        f32x4 v;
        v[0] = o[cb][4 * j + 0]; v[1] = o[cb][4 * j + 1];
        v[2] = o[cb][4 * j + 2]; v[3] = o[cb][4 * j + 3];
        *(f32x4*)(tb + qcol * 128 + (((2 * j + hi) ^ (qcol & 7)) << 4)) = v;
      }
#pragma unroll
      for (int jr = 0; jr < 4; ++jr) {
        int qr = jr * 8 + (ln >> 3), cc = ln & 7;
        f32x4 v = *(const f32x4*)(tb + qr * 128 + ((cc ^ (qr & 7)) << 4));
        S4 sv; sv.x = f2bf(v[0]); sv.y = f2bf(v[1]); sv.z = f2bf(v[2]); sv.w = f2bf(v[3]);
        *(S4*)(po + ((size_t)kz * NROWS + rb + qr) * CC + cb * 32 + cc * 4) = sv;
      }
    }
    if (ln < 32) {
      pl[(size_t)kz * NROWS + rb + qcol] = lsum;
    }
  }
}

// ---------------- epilogue: combine partials + relu(BN((q-xr) wt^T)+..) + q --
__global__ __launch_bounds__(256)
void k_epilogue(const float* __restrict__ q, const float* __restrict__ xr,
                const short* __restrict__ po, const float* __restrict__ pl,
                const short* __restrict__ wtb, const float* __restrict__ scale,
                const float* __restrict__ bias, float* __restrict__ out,
                int nsplit) {
  const int lane = threadIdx.x & 63, w = threadIdx.x >> 6;
  const int rowbase = blockIdx.x * 64 + w * 16;
  const int cb = blockIdx.y * 128;
  const int lr = lane & 15, lg = lane >> 4;
  float invL = 1.f;
  if (nsplit > 1) {
    float L = 0.f;
#pragma unroll
    for (int z = 0; z < 4; ++z) L += pl[(size_t)z * NROWS + rowbase + lr];
    invL = 1.f / L;
  }
  f32x4 acc[8] = {};
#pragma unroll
  for (int kf = 0; kf < 8; ++kf) {
    size_t base = (size_t)(rowbase + lr) * CC + kf * 32 + lg * 8;
    float4 q0 = *(const float4*)(q + base), q1 = *(const float4*)(q + base + 4);
    float xv[8];
    if (nsplit > 1) {
#pragma unroll
      for (int j = 0; j < 8; ++j) xv[j] = 0.f;
#pragma unroll
      for (int z = 0; z < 4; ++z) {
        bf16x8 t = *(const bf16x8*)(po + (size_t)z * NROWS * CC + base);
#pragma unroll
        for (int j = 0; j < 8; ++j) xv[j] += bf2f(t[j]);
      }
#pragma unroll
      for (int j = 0; j < 8; ++j) xv[j] *= invL;
    } else {
      float4 r0 = *(const float4*)(xr + base), r1 = *(const float4*)(xr + base + 4);
      xv[0] = r0.x; xv[1] = r0.y; xv[2] = r0.z; xv[3] = r0.w;
      xv[4] = r1.x; xv[5] = r1.y; xv[6] = r1.z; xv[7] = r1.w;
    }
    bf16x8 a;
    a[0] = f2bf(q0.x - xv[0]); a[1] = f2bf(q0.y - xv[1]);
    a[2] = f2bf(q0.z - xv[2]); a[3] = f2bf(q0.w - xv[3]);
    a[4] = f2bf(q1.x - xv[4]); a[5] = f2bf(q1.y - xv[5]);
    a[6] = f2bf(q1.z - xv[6]); a[7] = f2bf(q1.w - xv[7]);
#pragma unroll
    for (int nf = 0; nf < 8; ++nf) {
      bf16x8 b = *(const bf16x8*)(wtb + (size_t)(cb + nf * 16 + lr) * CC + kf * 32 + lg * 8);
      acc[nf] = mfma16(a, b, acc[nf]);
    }
  }
#pragma unroll
  for (int nf = 0; nf < 8; ++nf) {
    int c = cb + nf * 16 + lr;
    float sc = scale[c], bi = bias[c];
#pragma unroll
    for (int r = 0; r < 4; ++r) {
      int row = rowbase + lg * 4 + r;
      float y = acc[nf][r] * sc + bi;
      y = fmaxf(y, 0.f) + q[(size_t)row * CC + c];
      out[(size_t)row * CC + c] = y;
    }
  }
}

// ---------------- launch -----------------------------------------------------
extern "C" void kernel_launch(void* const* d_in, const int* in_sizes, int n_in,
                              void* d_out, int out_size, void* d_ws, size_t ws_size,
                              hipStream_t stream) {
  const float* q     = (const float*)d_in[0];
  const float* kv    = (const float*)d_in[1];
  const float* wq    = (const float*)d_in[2];
  const float* wk    = (const float*)d_in[3];
  const float* wv    = (const float*)d_in[4];
  const float* wt    = (const float*)d_in[5];
  const float* bt    = (const float*)d_in[6];
  const float* gmm   = (const float*)d_in[7];
  const float* bet   = (const float*)d_in[8];
  const float* rmean = (const float*)d_in[9];
  const float* rvar  = (const float*)d_in[10];
  float* out = (float*)d_out;
  char* ws = (char*)d_ws;

  short* wqb  = (short*)(ws + 0);         // 32 KB
  short* wkb  = (short*)(ws + 32768);     // 32 KB
  short* wvb  = (short*)(ws + 65536);     // 128 KB
  short* wtb  = (short*)(ws + 196608);    // 128 KB
  float* scale= (float*)(ws + 327680);    // 1 KB
  float* bias = (float*)(ws + 328704);    // 1 KB
  short* xq   = (short*)(ws + 329728);    // 2 MB
  short* xk   = (short*)(ws + 2426880);   // 2 MB
  short* vt   = (short*)(ws + 4524032);   // 8 MB
  float* xr   = (float*)(ws + 12912640);  // 16 MB
  short* po   = (short*)(ws + 29689856);  // 32 MB (4 x 16384 x 256 bf16)
  float* pl   = (float*)(ws + 63244288);  // 256 KB
  const size_t NEED = 63506432;
  const int nsplit = (ws_size >= NEED) ? 4 : 1;

  k_setup<<<256, 256, 0, stream>>>(wq, wk, wv, wt, bt, gmm, bet, rmean, rvar,
                                   wqb, wkb, wvb, wtb, scale, bias);
  k_proj<<<dim3(256, 3), 256, 0, stream>>>(q, kv, wqb, wkb, wvb, xq, xk, vt);
  k_attn<<<dim3(64, 2, nsplit), 256, 0, stream>>>(xq, xk, vt, xr, po, pl, nsplit);
  k_epilogue<<<dim3(256, 2), 256, 0, stream>>>(q, xr, po, pl, wtb, scale, bias, out, nsplit);
}